// Round 1
// baseline (53.094 us; speedup 1.0000x reference)
//
#include <hip/hip_runtime.h>
#include <math.h>

#define QMAX 128      // wavelet support: gauss fp32-underflows to exact 0 beyond t~82
#define CHUNK 2048    // outputs per block
#define RPT 8         // outputs per thread (256 threads * 8 = 2048)

// ---------------- Kernel 1: build W[16][QMAX] ----------------
__global__ void wavelet_build(const float* __restrict__ scales,
                              const float* __restrict__ f_mod,
                              const float* __restrict__ poly_mod,
                              const float* __restrict__ exp_mod,
                              const float* __restrict__ frac_order,
                              const float* __restrict__ phase_mod,
                              const int* __restrict__ istep,
                              float* __restrict__ Wout) {
    const int k = blockIdx.x;   // scale 0..15
    const int t = threadIdx.x;  // 0..127
    const int i = istep[0];
    const float PI2 = 6.28318530717958647692f;

    const float scale = scales[k];
    const float f = 1.0f / scale;
    const float fm = f_mod[i];
    const float* pm = poly_mod + i * 14;
    const float em0 = exp_mod[i];
    const float* fo = frac_order + i * 12;
    const float* ph = phase_mod + i * 3;

    const float sigma = fmaxf(fm / (PI2 * f), 1e-6f);
    const float tf = (float)t;
    const float arg = PI2 * f * tf;
    const float br = cosf(arg);
    const float bi = sinf(arg);

    // real polynomial: pm[0] + sum_j sign_j * c^2 * t^fo[j] / sigma^fo[j] * pm[j+1]
    float rp = pm[0];
    float sign = -1.0f;
    for (int j = 0; j < 6; ++j) {
        float c = (float)(j + 2);
        float sp = (tf > 0.0f) ? powf(tf, fo[j]) : 0.0f;
        float term = sp * c / powf(sigma, fo[j]) * c * pm[j + 1];
        rp += sign * term;
        sign = -sign;
    }
    // imag polynomial
    float ipoly = pm[7];
    sign = -1.0f;
    for (int j = 6; j < 12; ++j) {
        float sp = (tf > 0.0f) ? powf(tf, fo[j]) : 0.0f;
        float term;
        if (j == 9) {
            term = sp * 5.0f / (powf(sigma, fo[j]) * 5.0f) * pm[j + 2];
        } else {
            float c = (float)(j - 4);
            term = sp * c / powf(sigma, fo[j]) * c * pm[j + 2];
        }
        ipoly += sign * term;
        sign = -sign;
    }

    const float gauss = em0 * expf(-tf * tf / (2.0f * sigma * sigma));
    const float rw = br * rp * gauss;
    const float iw = bi * ipoly * gauss;
    const float amp = rw + iw;

    // norm over full t-axis == norm over [0,128) since amp==0 beyond support
    float sq = amp * amp;
    #pragma unroll
    for (int off = 32; off > 0; off >>= 1) sq += __shfl_xor(sq, off, 64);
    __shared__ float wsum[2];
    if ((t & 63) == 0) wsum[t >> 6] = sq;
    __syncthreads();
    const float norm = sqrtf(wsum[0] + wsum[1]);

    const float samp = amp / norm;
    const float phase = atan2f(iw, rw);
    const float sphi = sinf(phase);
    const float cphi = cosf(phase);
    const float snc = (phase != 0.0f) ? (sphi / phase) : 1.0f;  // sinc(phase/pi)
    const float w = (samp * sphi * ph[0]) * (samp * cphi * ph[1]) * (samp * snc * ph[2]);
    Wout[k * QMAX + t] = w;
}

// ---------------- Kernel 2: FIR conv + 16x channel replication ----------------
// y[b,k,p] = sum_{q=0}^{QMAX-1} x[b,k,p+q-2047] * W[k,q]   (zero-padded x)
// out[b, r*16+k, p] = y[b,k,p]  for r=0..15
__global__ __launch_bounds__(256) void conv_rep(const float* __restrict__ x,
                                                const float* __restrict__ W,
                                                float* __restrict__ out) {
    __shared__ __attribute__((aligned(16))) float xs[CHUNK + QMAX];
    __shared__ __attribute__((aligned(16))) float Wl[QMAX];

    const int bk = blockIdx.y;       // 0..255 = b*16 + k
    const int b = bk >> 4;
    const int k = bk & 15;
    const int p0 = blockIdx.x * CHUNK;
    const int tid = threadIdx.x;

    const float* xrow = x + (size_t)bk * 4096;  // x[b][k][:]

    if (tid < QMAX) Wl[tid] = W[k * QMAX + tid];
    // stage x window [p0-2047, p0-2047+CHUNK+QMAX)
    for (int li = tid; li < CHUNK + QMAX; li += 256) {
        int g = p0 - 2047 + li;
        xs[li] = (g >= 0 && g < 4096) ? xrow[g] : 0.0f;
    }
    __syncthreads();

    const int base = tid * RPT;
    float acc[RPT];
    #pragma unroll
    for (int r = 0; r < RPT; ++r) acc[r] = 0.0f;

    for (int q = 0; q < QMAX; q += 4) {
        float4 w4 = *(const float4*)&Wl[q];
        float4 a0 = *(const float4*)&xs[base + q];       // base%8==0, q%4==0 -> 16B aligned
        float4 a1 = *(const float4*)&xs[base + q + 4];
        float4 a2 = *(const float4*)&xs[base + q + 8];
        float win[12] = {a0.x, a0.y, a0.z, a0.w,
                         a1.x, a1.y, a1.z, a1.w,
                         a2.x, a2.y, a2.z, a2.w};
        float wv[4] = {w4.x, w4.y, w4.z, w4.w};
        #pragma unroll
        for (int j = 0; j < 4; ++j) {
            #pragma unroll
            for (int r = 0; r < RPT; ++r) {
                acc[r] = fmaf(win[r + j], wv[j], acc[r]);
            }
        }
    }

    // replicate to the 16 output channels j = r*16 + k
    #pragma unroll
    for (int v = 0; v < RPT; v += 4) {
        float4 val = make_float4(acc[v], acc[v + 1], acc[v + 2], acc[v + 3]);
        const int p = p0 + base + v;
        #pragma unroll
        for (int r = 0; r < 16; ++r) {
            size_t oidx = ((size_t)b * 256 + r * 16 + k) * 4096 + p;
            *(float4*)&out[oidx] = val;
        }
    }
}

extern "C" void kernel_launch(void* const* d_in, const int* in_sizes, int n_in,
                              void* d_out, int out_size, void* d_ws, size_t ws_size,
                              hipStream_t stream) {
    const float* x          = (const float*)d_in[0];
    const float* scales     = (const float*)d_in[1];
    const float* f_mod      = (const float*)d_in[2];
    const float* poly_mod   = (const float*)d_in[3];
    const float* exp_mod    = (const float*)d_in[4];
    const float* frac_order = (const float*)d_in[5];
    const float* phase_mod  = (const float*)d_in[6];
    const int*   istep      = (const int*)d_in[7];
    float* out = (float*)d_out;
    float* Wbuf = (float*)d_ws;  // 16*128 floats = 8 KB

    wavelet_build<<<dim3(16), dim3(QMAX), 0, stream>>>(
        scales, f_mod, poly_mod, exp_mod, frac_order, phase_mod, istep, Wbuf);

    conv_rep<<<dim3(4096 / CHUNK, 256), dim3(256), 0, stream>>>(x, Wbuf, out);
}

// Round 2
// 36.170 us; speedup vs baseline: 1.4679x; 1.4679x over previous
//
#include <hip/hip_runtime.h>
#include <math.h>

#define QMAX 128      // wavelet support: gauss fp32-underflows to exact 0 beyond t~82
#define CHUNK 1024    // outputs per block (256 threads x 1 float4)
#define ZCUT 1920     // outputs p < ZCUT are exactly zero (x index p-1920 < 0)

// ---------------- Kernel 1: build W[16][QMAX] ----------------
__global__ void wavelet_build(const float* __restrict__ scales,
                              const float* __restrict__ f_mod,
                              const float* __restrict__ poly_mod,
                              const float* __restrict__ exp_mod,
                              const float* __restrict__ frac_order,
                              const float* __restrict__ phase_mod,
                              const int* __restrict__ istep,
                              float* __restrict__ Wout) {
    const int k = blockIdx.x;   // scale 0..15
    const int t = threadIdx.x;  // 0..127
    const int i = istep[0];
    const float PI2 = 6.28318530717958647692f;

    const float scale = scales[k];
    const float f = 1.0f / scale;
    const float fm = f_mod[i];
    const float* pm = poly_mod + i * 14;
    const float em0 = exp_mod[i];
    const float* fo = frac_order + i * 12;
    const float* ph = phase_mod + i * 3;

    const float sigma = fmaxf(fm / (PI2 * f), 1e-6f);
    const float tf = (float)t;
    const float arg = PI2 * f * tf;
    const float br = cosf(arg);
    const float bi = sinf(arg);

    float rp = pm[0];
    float sign = -1.0f;
    for (int j = 0; j < 6; ++j) {
        float c = (float)(j + 2);
        float sp = (tf > 0.0f) ? powf(tf, fo[j]) : 0.0f;
        float term = sp * c / powf(sigma, fo[j]) * c * pm[j + 1];
        rp += sign * term;
        sign = -sign;
    }
    float ipoly = pm[7];
    sign = -1.0f;
    for (int j = 6; j < 12; ++j) {
        float sp = (tf > 0.0f) ? powf(tf, fo[j]) : 0.0f;
        float term;
        if (j == 9) {
            term = sp * 5.0f / (powf(sigma, fo[j]) * 5.0f) * pm[j + 2];
        } else {
            float c = (float)(j - 4);
            term = sp * c / powf(sigma, fo[j]) * c * pm[j + 2];
        }
        ipoly += sign * term;
        sign = -sign;
    }

    const float gauss = em0 * expf(-tf * tf / (2.0f * sigma * sigma));
    const float rw = br * rp * gauss;
    const float iw = bi * ipoly * gauss;
    const float amp = rw + iw;

    float sq = amp * amp;
    #pragma unroll
    for (int off = 32; off > 0; off >>= 1) sq += __shfl_xor(sq, off, 64);
    __shared__ float wsum[2];
    if ((t & 63) == 0) wsum[t >> 6] = sq;
    __syncthreads();
    const float norm = sqrtf(wsum[0] + wsum[1]);

    const float samp = amp / norm;
    const float phase = atan2f(iw, rw);
    const float sphi = sinf(phase);
    const float cphi = cosf(phase);
    const float snc = (phase != 0.0f) ? (sphi / phase) : 1.0f;  // sinc(phase/pi)
    const float w = (samp * sphi * ph[0]) * (samp * cphi * ph[1]) * (samp * snc * ph[2]);
    Wout[k * QMAX + t] = w;
}

// ---------------- Kernel 2: FIR conv + 16x channel replication ----------------
// y[b,k,p] = sum_{q=0}^{QMAX-1} x[b,k,p+q-2047] * W[k,q]   (zero-padded x)
// p < ZCUT -> exact zero. out[b, r*16+k, p] = y[b,k,p] for r=0..15.
// Thread tid owns the single float4 at p = p0 + 4*tid -> every store
// instruction is a contiguous 1KB wave segment (fully coalesced).
__global__ __launch_bounds__(256) void conv_rep(const float* __restrict__ x,
                                                const float* __restrict__ W,
                                                float* __restrict__ out) {
    __shared__ __attribute__((aligned(16))) float xs[CHUNK + QMAX];
    __shared__ __attribute__((aligned(16))) float Wl[QMAX];

    const int bk = blockIdx.y;       // 0..255 = b*16 + k
    const int b = bk >> 4;
    const int k = bk & 15;
    const int p0 = blockIdx.x * CHUNK;
    const int tid = threadIdx.x;
    const int p = p0 + 4 * tid;

    float4 val = make_float4(0.0f, 0.0f, 0.0f, 0.0f);

    if (p0 + CHUNK > ZCUT) {  // block-uniform: any non-zero outputs in this chunk?
        if (tid < QMAX) Wl[tid] = W[k * QMAX + tid];
        const float* xrow = x + (size_t)bk * 4096;
        for (int li = tid; li < CHUNK + QMAX; li += 256) {
            int g = p0 - 2047 + li;
            xs[li] = (g >= 0 && g < 4096) ? xrow[g] : 0.0f;
        }
        __syncthreads();

        if (p >= ZCUT) {  // ZCUT % 4 == 0, so this is exact per-float4
            float acc[4] = {0.0f, 0.0f, 0.0f, 0.0f};
            const int base = 4 * tid;
            for (int q = 0; q < QMAX; q += 4) {
                float4 w4 = *(const float4*)&Wl[q];
                float4 x0 = *(const float4*)&xs[base + q];      // 16B aligned
                float4 x1 = *(const float4*)&xs[base + q + 4];
                float win[8] = {x0.x, x0.y, x0.z, x0.w,
                                x1.x, x1.y, x1.z, x1.w};
                float wv[4] = {w4.x, w4.y, w4.z, w4.w};
                #pragma unroll
                for (int j = 0; j < 4; ++j) {
                    #pragma unroll
                    for (int r = 0; r < 4; ++r) {
                        acc[r] = fmaf(win[r + j], wv[j], acc[r]);
                    }
                }
            }
            val = make_float4(acc[0], acc[1], acc[2], acc[3]);
        }
    }

    // replicate to the 16 output channels j = r*16 + k; coalesced per instruction
    #pragma unroll
    for (int r = 0; r < 16; ++r) {
        size_t oidx = ((size_t)b * 256 + (size_t)(r * 16 + k)) * 4096 + p;
        *(float4*)&out[oidx] = val;
    }
}

extern "C" void kernel_launch(void* const* d_in, const int* in_sizes, int n_in,
                              void* d_out, int out_size, void* d_ws, size_t ws_size,
                              hipStream_t stream) {
    const float* x          = (const float*)d_in[0];
    const float* scales     = (const float*)d_in[1];
    const float* f_mod      = (const float*)d_in[2];
    const float* poly_mod   = (const float*)d_in[3];
    const float* exp_mod    = (const float*)d_in[4];
    const float* frac_order = (const float*)d_in[5];
    const float* phase_mod  = (const float*)d_in[6];
    const int*   istep      = (const int*)d_in[7];
    float* out = (float*)d_out;
    float* Wbuf = (float*)d_ws;  // 16*128 floats = 8 KB

    wavelet_build<<<dim3(16), dim3(QMAX), 0, stream>>>(
        scales, f_mod, poly_mod, exp_mod, frac_order, phase_mod, istep, Wbuf);

    conv_rep<<<dim3(4096 / CHUNK, 256), dim3(256), 0, stream>>>(x, Wbuf, out);
}